// Round 6
// baseline (182.201 us; speedup 1.0000x reference)
//
#include <hip/hip_runtime.h>
#include <stdint.h>

#define T_STEPS 512
#define BATCH   512
#define IN_DIM  128
#define GDIM    32   // 4 gates x 8 qubits
#define SLICE   (BATCH * GDIM)   // 16384 floats per time step
#define INV2PI  0.15915494309189535f

typedef float f4 __attribute__((ext_vector_type(4)));

// ---------------------------------------------------------------------------
// DPP helper: quad_perm bcast j: ctrl=j*0x55 ; row_shr:k=0x110|k ;
// row_ror:8=0x128 ; row_half_mirror=0x141.
// ---------------------------------------------------------------------------
template <int CTRL>
__device__ __forceinline__ float dppm(float x) {
    return __int_as_float(__builtin_amdgcn_mov_dpp(__float_as_int(x), CTRL, 0xF, 0xF, true));
}

// tanh Pade[5/4]: x(945+105u+u^2)/(945+420u+15u^2), u=x^2. err<=5e-5 on [-2.2,2.2].
__device__ __forceinline__ float tanh_pade(float x) {
    float u = x * x;
    float n = fmaf(u, u + 105.0f, 945.0f);
    float d = fmaf(u, fmaf(u, 15.0f, 420.0f), 945.0f);
    return (x * n) * __builtin_amdgcn_rcpf(d);
}

// async global->LDS, 16 bytes per lane: LDS dest = base + lane*16
__device__ __forceinline__ void gload_lds16(const float* g, float* l) {
    __builtin_amdgcn_global_load_lds(
        (const __attribute__((address_space(1))) void*)g,
        (__attribute__((address_space(3))) void*)l, 16, 0, 0);
}

// ---------------------------------------------------------------------------
// Kernel 1 (unchanged from round 4, known-good):
// X[row][g] = (inp[row].W_gate[:,q] + b_gate[q] + theta_gate[q]) / 2pi
// 64 rows/block, 4 waves, wave = gate (W stays on the wave-uniform s_load path).
// ---------------------------------------------------------------------------
__global__ __launch_bounds__(256) void qlstm_xproj(
    const float* __restrict__ inp,
    const float* __restrict__ Wf, const float* __restrict__ bf,
    const float* __restrict__ Wi, const float* __restrict__ bi,
    const float* __restrict__ Wu, const float* __restrict__ bu,
    const float* __restrict__ Wo, const float* __restrict__ bo,
    const float* __restrict__ thf, const float* __restrict__ thi,
    const float* __restrict__ thu, const float* __restrict__ tho,
    float* __restrict__ X)
{
    __shared__ float tile[64 * 129];
    const int tid = threadIdx.x;
    const long long row0 = (long long)blockIdx.x * 64;

    const f4* src = (const f4*)(inp + row0 * IN_DIM);
    #pragma unroll
    for (int i = 0; i < 8; ++i) {
        int f = tid + i * 256;            // 0..2047
        f4 v = __builtin_nontemporal_load(src + f);
        int r = f >> 5, c = (f & 31) << 2;
        float* d = &tile[r * 129 + c];
        d[0] = v.x; d[1] = v.y; d[2] = v.z; d[3] = v.w;
    }
    __syncthreads();

    const int g  = __builtin_amdgcn_readfirstlane(tid >> 6);  // wave id = gate
    const int rl = tid & 63;

    const float* W  = (g == 0) ? Wf : (g == 1) ? Wi : (g == 2) ? Wu : Wo;
    const float* B  = (g == 0) ? bf : (g == 1) ? bi : (g == 2) ? bu : bo;
    const float* TH = (g == 0) ? thf : (g == 1) ? thi : (g == 2) ? thu : tho;

    float acc[8];
    #pragma unroll
    for (int j = 0; j < 8; ++j) acc[j] = B[j] + TH[j];

    #pragma unroll 8
    for (int k = 0; k < IN_DIM; ++k) {
        float v = tile[rl * 129 + k];     // banks (rl+k)%32: 2-way = free
        #pragma unroll
        for (int j = 0; j < 8; ++j)
            acc[j] = fmaf(v, W[k * 8 + j], acc[j]);   // uniform -> s_load
    }

    float4* Xo = (float4*)(X + (row0 + rl) * GDIM + g * 8);
    Xo[0] = make_float4(acc[0] * INV2PI, acc[1] * INV2PI, acc[2] * INV2PI, acc[3] * INV2PI);
    Xo[1] = make_float4(acc[4] * INV2PI, acc[5] * INV2PI, acc[6] * INV2PI, acc[7] * INV2PI);
}

// ---------------------------------------------------------------------------
// Kernel 2: serial recurrence, r4-proven chain body. ONE structural change vs
// r4: the batch's whole X column (512 steps x 32 floats = 64 KB) is staged
// into LDS up-front via 64 global_load_lds(16B) + one vmcnt(0). Steady state
// reads only LDS (ds_read ~120cy, hidden by 2-step register lookahead).
// One batch per wave, 512 blocks, 64KB LDS -> 2 blocks/CU (matches grid).
// ---------------------------------------------------------------------------
__global__ __launch_bounds__(64, 1) void qlstm_rec(
    const float* __restrict__ X,
    const float* __restrict__ Wf, const float* __restrict__ Wi,
    const float* __restrict__ Wu, const float* __restrict__ Wo,
    float* __restrict__ out)
{
    __shared__ float xb[T_STEPS * GDIM];   // 64 KB, fully overwritten below

    const int lane = threadIdx.x;
    const int l16  = lane & 15;
    const int q    = lane & 7;
    const int gA   = (lane >> 3) & 1;
    const int b    = blockIdx.x;

    const bool ql   = ((lane >> 2) & 1) == 0;  // low quad of 8-group
    const bool lo8  = (l16 < 8);
    const bool st8  = (lane < 8);
    const bool ge1  = (q >= 1), ge2 = (q >= 2), ge4 = (q >= 4);
    const bool isq0 = (q == 0);

    // ---- stage all 512 steps of this batch's X column ----
    // load n: lane i <- X[step 8n+(i>>3)][col 4*(i&7)..+3] of batch b
    //         -> xb[n*256 + 4i] ; linear layout xb[step*32 + col].
    {
        const float* g0 = X + b * GDIM + (lane >> 3) * SLICE + (lane & 7) * 4;
        #pragma unroll
        for (int n = 0; n < 64; ++n)
            gload_lds16(g0 + n * 8 * SLICE, &xb[n * 256]);
    }

    // weights (normal VGPR loads; compiler inserts its own waits)
    const float* WA = gA ? Wi : Wf;
    const float* WB = gA ? Wo : Wu;
    float wA[8], wB[8];
    #pragma unroll
    for (int k = 0; k < 8; ++k) {
        wA[k] = WA[(IN_DIM + k) * 8 + q] * INV2PI;
        wB[k] = WB[(IN_DIM + k) * 8 + q] * INV2PI;
    }

    asm volatile("s_waitcnt vmcnt(0)" ::: "memory");
    __builtin_amdgcn_sched_barrier(0);

    float hx = 0.0f, cx = 0.0f;

    // 2-step register lookahead from LDS
    float xA0 = xb[l16],       xB0 = xb[16 + l16];
    float xA1 = xb[32 + l16],  xB1 = xb[48 + l16];

    float* outp = out + b * 8 + q;

    #define QSTEP(T, XVA, XVB, TP)                                              \
    {                                                                           \
        const int t_ = (T);                                                     \
        float xvA = (XVA), xvB = (XVB);                                         \
        const int tp_ = ((T) + 2) & (T_STEPS - 1);                              \
        (XVA) = xb[tp_ * 32 + l16];                                             \
        (XVB) = xb[tp_ * 32 + 16 + l16];                                        \
        (void)(TP);                                                             \
        /* R1: broadcast hx[0..7] within 8-group */                             \
        float a0 = dppm<0x00>(hx), b0 = dppm<0x141>(a0);                        \
        float a1 = dppm<0x55>(hx), b1 = dppm<0x141>(a1);                        \
        float a2 = dppm<0xAA>(hx), b2 = dppm<0x141>(a2);                        \
        float a3 = dppm<0xFF>(hx), b3 = dppm<0x141>(a3);                        \
        float h0 = ql ? a0 : b0, h4 = ql ? b0 : a0;                             \
        float h1 = ql ? a1 : b1, h5 = ql ? b1 : a1;                             \
        float h2 = ql ? a2 : b2, h6 = ql ? b2 : a2;                             \
        float h3 = ql ? a3 : b3, h7 = ql ? b3 : a3;                             \
        float zA = xvA + (((h0 * wA[0] + h1 * wA[1]) + (h2 * wA[2] + h3 * wA[3])) \
                        + ((h4 * wA[4] + h5 * wA[5]) + (h6 * wA[6] + h7 * wA[7]))); \
        float zB = xvB + (((h0 * wB[0] + h1 * wB[1]) + (h2 * wB[2] + h3 * wB[3])) \
                        + ((h4 * wB[4] + h5 * wB[5]) + (h6 * wB[6] + h7 * wB[7]))); \
        float cA = __builtin_amdgcn_cosf(zA);                                   \
        float cB = __builtin_amdgcn_cosf(zB);                                   \
        /* prefix scan: P_j = c0..cj */                                         \
        float PA = cA, PB = cB, tv;                                             \
        tv = dppm<0x111>(PA); PA *= (ge1 ? tv : 1.0f);                          \
        tv = dppm<0x111>(PB); PB *= (ge1 ? tv : 1.0f);                          \
        tv = dppm<0x112>(PA); PA *= (ge2 ? tv : 1.0f);                          \
        tv = dppm<0x112>(PB); PB *= (ge2 ? tv : 1.0f);                          \
        tv = dppm<0x114>(PA); PA *= (ge4 ? tv : 1.0f);                          \
        tv = dppm<0x114>(PB); PB *= (ge4 ? tv : 1.0f);                          \
        /* lane0: out0 = (c0..c7) * rcp(c0), rcp parallel to the scan */        \
        float fullA = dppm<0x141>(PA);                                          \
        float fullB = dppm<0x141>(PB);                                          \
        float cAc = fabsf(cA) < 1e-30f ? 1e-30f : cA;                           \
        float cBc = fabsf(cB) < 1e-30f ? 1e-30f : cB;                           \
        float outA = isq0 ? fullA * __builtin_amdgcn_rcpf(cAc) : PA;            \
        float outB = isq0 ? fullB * __builtin_amdgcn_rcpf(cBc) : PB;            \
        /* activations via shared tanh Pade */                                  \
        float actA = fmaf(tanh_pade(outA * 0.5f), 0.5f, 0.5f);                  \
        float actB = fmaf(tanh_pade(outB * sB), aB, bB);                        \
        /* R3: gather f,i,u,o for unit q */                                     \
        float rA = dppm<0x128>(actA);                                           \
        float rB = dppm<0x128>(actB);                                           \
        float fv = lo8 ? actA : rA;                                             \
        float iv = lo8 ? rA : actA;                                             \
        float uv = lo8 ? actB : rB;                                             \
        float ov = lo8 ? rB : actB;                                             \
        float ncx = fmaf(fv, cx, iv * uv);                                      \
        float nhx = ov * tanh_pade(ncx);                                        \
        cx = ncx;                                                               \
        hx = nhx;                                                               \
        if (st8) __builtin_nontemporal_store(nhx, outp + t_ * (BATCH * 8));     \
    }

    // B-stream activation fold: lo8 = u-gate (tanh), hi8 = o-gate (sigmoid)
    const float sB = lo8 ? 1.0f : 0.5f;
    const float aB = lo8 ? 1.0f : 0.5f;
    const float bB = lo8 ? 0.0f : 0.5f;

    for (int t = 0; t < T_STEPS; t += 2) {
        QSTEP(t,     xA0, xB0, 0)
        QSTEP(t + 1, xA1, xB1, 0)
    }
    #undef QSTEP

    if (st8) {
        __builtin_nontemporal_store(hx, out + T_STEPS * BATCH * 8 + b * 8 + q);
        __builtin_nontemporal_store(cx, out + T_STEPS * BATCH * 8 + (BATCH + b) * 8 + q);
    }
}

// ---------------------------------------------------------------------------
extern "C" void kernel_launch(void* const* d_in, const int* in_sizes, int n_in,
                              void* d_out, int out_size, void* d_ws, size_t ws_size,
                              hipStream_t stream) {
    const float* inp = (const float*)d_in[0];
    const float* Wf  = (const float*)d_in[1];
    const float* bf  = (const float*)d_in[2];
    const float* Wi  = (const float*)d_in[3];
    const float* bi  = (const float*)d_in[4];
    const float* Wu  = (const float*)d_in[5];
    const float* bu  = (const float*)d_in[6];
    const float* Wo  = (const float*)d_in[7];
    const float* bo  = (const float*)d_in[8];
    const float* thf = (const float*)d_in[9];
    const float* thi = (const float*)d_in[10];
    const float* thu = (const float*)d_in[11];
    const float* tho = (const float*)d_in[12];

    float* X   = (float*)d_ws;              // (T*B, 32) fp32 = 33.5 MB
    float* out = (float*)d_out;

    qlstm_xproj<<<(T_STEPS * BATCH) / 64, 256, 0, stream>>>(
        inp, Wf, bf, Wi, bi, Wu, bu, Wo, bo, thf, thi, thu, tho, X);

    qlstm_rec<<<BATCH, 64, 0, stream>>>(X, Wf, Wi, Wu, Wo, out);
}

// Round 8
// 152.911 us; speedup vs baseline: 1.1916x; 1.1916x over previous
//
#include <hip/hip_runtime.h>
#include <stdint.h>

#define T_STEPS 512
#define BATCH   512
#define IN_DIM  128
#define GDIM    32   // 4 gates x 8 qubits
#define SLICE   (BATCH * GDIM)   // 16384 floats per time step
#define INV2PI  0.15915494309189535f

typedef float f4 __attribute__((ext_vector_type(4)));

// ---------------------------------------------------------------------------
// DPP helpers. quad_perm: ctrl 0x00-0xFF (sel per lane-in-quad);
// row_shl:k = 0x100|k ; row_shr:k = 0x110|k ; row_mirror = 0x140 ;
// row_half_mirror = 0x141.
// ---------------------------------------------------------------------------
template <int CTRL>
__device__ __forceinline__ float dppm(float x) {
    return __int_as_float(__builtin_amdgcn_mov_dpp(__float_as_int(x), CTRL, 0xF, 0xF, true));
}
// keep-old semantics: lanes with OOB dpp source keep `old` (bound_ctrl=false)
template <int CTRL>
__device__ __forceinline__ float dppk(float old, float x) {
    return __int_as_float(__builtin_amdgcn_update_dpp(
        __float_as_int(old), __float_as_int(x), CTRL, 0xF, 0xF, false));
}

// tanh Pade[5/4]: x(945+105u+u^2)/(945+420u+15u^2), u=x^2. err<=5e-5 on [-2.2,2.2].
__device__ __forceinline__ float tanh_pade(float x) {
    float u = x * x;
    float n = fmaf(u, u + 105.0f, 945.0f);
    float d = fmaf(u, fmaf(u, 15.0f, 420.0f), 945.0f);
    return (x * n) * __builtin_amdgcn_rcpf(d);
}

// async global->LDS, 16 bytes per lane: LDS dest = base + lane*16
__device__ __forceinline__ void gload_lds16(const float* g, float* l) {
    __builtin_amdgcn_global_load_lds(
        (const __attribute__((address_space(1))) void*)g,
        (__attribute__((address_space(3))) void*)l, 16, 0, 0);
}

// ---------------------------------------------------------------------------
// Kernel 1 (r4-proven, unchanged):
// X[row][g] = (inp[row].W_gate[:,q] + b_gate[q] + theta_gate[q]) / 2pi
// ---------------------------------------------------------------------------
__global__ __launch_bounds__(256) void qlstm_xproj(
    const float* __restrict__ inp,
    const float* __restrict__ Wf, const float* __restrict__ bf,
    const float* __restrict__ Wi, const float* __restrict__ bi,
    const float* __restrict__ Wu, const float* __restrict__ bu,
    const float* __restrict__ Wo, const float* __restrict__ bo,
    const float* __restrict__ thf, const float* __restrict__ thi,
    const float* __restrict__ thu, const float* __restrict__ tho,
    float* __restrict__ X)
{
    __shared__ float tile[64 * 129];
    const int tid = threadIdx.x;
    const long long row0 = (long long)blockIdx.x * 64;

    const f4* src = (const f4*)(inp + row0 * IN_DIM);
    #pragma unroll
    for (int i = 0; i < 8; ++i) {
        int f = tid + i * 256;            // 0..2047
        f4 v = __builtin_nontemporal_load(src + f);
        int r = f >> 5, c = (f & 31) << 2;
        float* d = &tile[r * 129 + c];
        d[0] = v.x; d[1] = v.y; d[2] = v.z; d[3] = v.w;
    }
    __syncthreads();

    const int g  = __builtin_amdgcn_readfirstlane(tid >> 6);  // wave id = gate
    const int rl = tid & 63;

    const float* W  = (g == 0) ? Wf : (g == 1) ? Wi : (g == 2) ? Wu : Wo;
    const float* B  = (g == 0) ? bf : (g == 1) ? bi : (g == 2) ? bu : bo;
    const float* TH = (g == 0) ? thf : (g == 1) ? thi : (g == 2) ? thu : tho;

    float acc[8];
    #pragma unroll
    for (int j = 0; j < 8; ++j) acc[j] = B[j] + TH[j];

    #pragma unroll 8
    for (int k = 0; k < IN_DIM; ++k) {
        float v = tile[rl * 129 + k];     // banks (rl+k)%32: 2-way = free
        #pragma unroll
        for (int j = 0; j < 8; ++j)
            acc[j] = fmaf(v, W[k * 8 + j], acc[j]);   // uniform -> s_load
    }

    float4* Xo = (float4*)(X + (row0 + rl) * GDIM + g * 8);
    Xo[0] = make_float4(acc[0] * INV2PI, acc[1] * INV2PI, acc[2] * INV2PI, acc[3] * INV2PI);
    Xo[1] = make_float4(acc[4] * INV2PI, acc[5] * INV2PI, acc[6] * INV2PI, acc[7] * INV2PI);
}

// ---------------------------------------------------------------------------
// Kernel 2: serial recurrence, single-stream layout (verified lane-by-lane):
// lane = (stream s = bit5)(batch bb = bit4)(quad qd = bits3:2)(pos p = bits3:0)
//   qubit q = p>>1, gate parity par = bit0; gate = 2s+par.
// One instruction covers all 4 gates x 8 qubits x 2 batches.
// - hx broadcast: 8 pure DPPs; selects folded into weight perm wv[i]=w[i^2qd].
// - prefix product: update_dpp row_shr:2/4/8, keep-old=1.0.
// - q=0 output: parallel strict suffix scan (row_shl, keep-old, OOB-safe).
// - cross-stream gather: __shfl_xor(act,32) — PROVEN primitive (r1/r2),
//   replacing round-7's unverified v_permlane32_swap asm (the one suspect).
// X staged via global_load_lds double-buffer (64KB, vmcnt(0) per 128 steps).
// ---------------------------------------------------------------------------
__global__ __launch_bounds__(64, 1) void qlstm_rec(
    const float* __restrict__ X,
    const float* __restrict__ Wf, const float* __restrict__ Wi,
    const float* __restrict__ Wu, const float* __restrict__ Wo,
    float* __restrict__ out)
{
    __shared__ float xb[2 * 2 * 128 * 32];   // [buf][batch][ls][col] = 64 KB

    const int lane = threadIdx.x;
    const int p    = lane & 15;
    const int q    = p >> 1;
    const int par  = lane & 1;
    const int s    = lane >> 5;
    const int bb   = (lane >> 4) & 1;
    const int qd   = (lane >> 2) & 3;
    const int gate = s * 2 + par;
    const int b    = blockIdx.x * 2 + bb;
    const int col  = s * 16 + par * 8 + q;

    const bool isq0   = (q == 0);
    const bool sB     = (s == 1);
    const bool parB   = (par == 1);
    const bool strow  = (lane < 32) && (par == 0);   // store lanes

    // per-lane gate weights, permuted to match the broadcast register order
    const float* Wg = (gate == 0) ? Wf : (gate == 1) ? Wi : (gate == 2) ? Wu : Wo;
    float wv[8];
    #pragma unroll
    for (int i = 0; i < 8; ++i)
        wv[i] = Wg[(IN_DIM + (i ^ (qd << 1))) * 8 + q] * INV2PI;

    // activation fold: sigma for f,i,o ; tanh for u
    const bool  isT = (gate == 2);
    const float sc  = isT ? 1.0f : 0.5f;
    const float aa  = isT ? 1.0f : 0.5f;
    const float bbv = isT ? 0.0f : 0.5f;

    // staging: load n of (buf, batch j) : lane i reads
    //   X[(qs + 8n + (i>>3))*SLICE + (2*blk+j)*32 + (i&7)*4 .. +3]
    const float* g0 = X + (lane >> 3) * SLICE + (lane & 7) * 4
                        + blockIdx.x * 2 * GDIM;
    auto stage = [&](int bi, int qs) {
        #pragma unroll
        for (int j = 0; j < 2; ++j) {
            float* dst = &xb[(bi * 2 + j) * 4096];
            const float* srcb = g0 + j * GDIM + qs * SLICE;
            #pragma unroll
            for (int n = 0; n < 16; ++n)
                gload_lds16(srcb + n * 8 * SLICE, dst + n * 256);
        }
    };

    stage(0, 0);
    asm volatile("s_waitcnt vmcnt(0)" ::: "memory");

    const float* xq0 = &xb[bb * 4096 + col];
    float xv0 = xq0[0];
    float xv1 = xq0[32];
    stage(1, 128);

    float hx = 0.0f, cx = 0.0f;
    const float ONE = 1.0f;
    float* outp = out + b * 8 + q;

    for (int qt = 0; qt < 4; ++qt) {
        const int bi = qt & 1;
        const float* xq = &xb[bi * 8192 + bb * 4096 + col];
        if (qt > 0) {
            asm volatile("s_waitcnt vmcnt(0)" ::: "memory");
            xv0 = xq[0];
            xv1 = xq[32];
            if (qt < 3) stage(1 - bi, (qt + 1) * 128);
        }

        auto qstep = [&](int t, int ls, float& XV) {
            float xv = XV;
            XV = xq[((ls + 2) & 127) * 32];       // lookahead refill (wrap-safe)

            // ---- hx broadcast: 8 DPPs, order folded into wv ----
            float Ba = dppm<0x00>(hx);            // h[2*quad]
            float Bb = dppm<0xAA>(hx);            // h[2*quad+1]
            float Bc = dppm<0x141>(Ba);           // h[2q^2]
            float Bd = dppm<0x141>(Bb);           // h[(2q^2)+1]
            float Be = dppm<0x140>(Ba);           // h[2q^6]
            float Bf = dppm<0x140>(Bb);           // h[(2q^6)+1]
            float Bg = dppm<0x141>(Be);           // h[2q^4]
            float Bk = dppm<0x141>(Bf);           // h[(2q^4)+1]

            float mA = fmaf(Ba, wv[0], xv);
            mA = fmaf(Bb, wv[1], mA);
            mA = fmaf(Bc, wv[2], mA);
            mA = fmaf(Bd, wv[3], mA);
            float mB = Be * wv[6];
            mB = fmaf(Bf, wv[7], mB);
            mB = fmaf(Bg, wv[4], mB);
            mB = fmaf(Bk, wv[5], mB);
            float z = mA + mB;

            float cq = __builtin_amdgcn_cosf(z);  // cos(2pi * z')

            // ---- prefix product P_q = c0..cq (stride-2 lanes, keep-old=1) ----
            float P = cq * dppk<0x112>(ONE, cq);
            P = P * dppk<0x114>(ONE, P);
            P = P * dppk<0x118>(ONE, P);

            // ---- strict suffix T_q = c_{q+1}..c7 (parallel to prefix) ----
            float T = dppk<0x102>(ONE, cq);
            T = T * dppk<0x102>(ONE, T);
            T = T * dppk<0x104>(ONE, T);
            T = T * dppk<0x108>(ONE, T);

            float outv = isq0 ? T : P;

            // ---- activation (pade; per-lane sigma/tanh fold) ----
            float act = fmaf(tanh_pade(outv * sc), aa, bbv);

            // ---- gather f,i,u,o for this unit ----
            float n1 = dppm<0xB1>(act);           // other parity, own stream
            float sw = __shfl_xor(act, 32, 64);   // other stream, same position
            float sw2 = dppm<0xB1>(sw);           // other stream, other parity

            float X1 = parB ? n1  : act;          // own-stream even gate
            float X2 = parB ? act : n1;           // own-stream odd gate
            float Y1 = parB ? sw2 : sw;           // other-stream even gate
            float Y2 = parB ? sw  : sw2;          // other-stream odd gate

            float fv = sB ? Y1 : X1;
            float iv = sB ? Y2 : X2;
            float uv = sB ? X1 : Y1;
            float ov = sB ? X2 : Y2;

            // ---- state update ----
            float ncx = fmaf(fv, cx, iv * uv);
            float nhx = ov * tanh_pade(ncx);
            cx = ncx;
            hx = nhx;

            if (strow) __builtin_nontemporal_store(nhx, outp + t * (BATCH * 8));
        };

        #pragma unroll 2
        for (int ls = 0; ls < 128; ls += 2) {
            qstep(qt * 128 + ls,     ls,     xv0);
            qstep(qt * 128 + ls + 1, ls + 1, xv1);
        }
    }

    if (strow) {
        __builtin_nontemporal_store(hx, out + T_STEPS * BATCH * 8 + b * 8 + q);
        __builtin_nontemporal_store(cx, out + T_STEPS * BATCH * 8 + (BATCH + b) * 8 + q);
    }
}

// ---------------------------------------------------------------------------
extern "C" void kernel_launch(void* const* d_in, const int* in_sizes, int n_in,
                              void* d_out, int out_size, void* d_ws, size_t ws_size,
                              hipStream_t stream) {
    const float* inp = (const float*)d_in[0];
    const float* Wf  = (const float*)d_in[1];
    const float* bf  = (const float*)d_in[2];
    const float* Wi  = (const float*)d_in[3];
    const float* bi  = (const float*)d_in[4];
    const float* Wu  = (const float*)d_in[5];
    const float* bu  = (const float*)d_in[6];
    const float* Wo  = (const float*)d_in[7];
    const float* bo  = (const float*)d_in[8];
    const float* thf = (const float*)d_in[9];
    const float* thi = (const float*)d_in[10];
    const float* thu = (const float*)d_in[11];
    const float* tho = (const float*)d_in[12];

    float* X   = (float*)d_ws;              // (T*B, 32) fp32 = 33.5 MB
    float* out = (float*)d_out;

    qlstm_xproj<<<(T_STEPS * BATCH) / 64, 256, 0, stream>>>(
        inp, Wf, bf, Wi, bi, Wu, bu, Wo, bo, thf, thi, thu, tho, X);

    qlstm_rec<<<BATCH / 2, 64, 0, stream>>>(X, Wf, Wi, Wu, Wo, out);
}

// Round 11
// 149.382 us; speedup vs baseline: 1.2197x; 1.0236x over previous
//
#include <hip/hip_runtime.h>
#include <stdint.h>

#define T_STEPS 512
#define BATCH   512
#define IN_DIM  128
#define GDIM    32   // 4 gates x 8 qubits
#define SLICE   (BATCH * GDIM)   // 16384 floats per time step
#define INV2PI  0.15915494309189535f

typedef float f4 __attribute__((ext_vector_type(4)));

// ---------------------------------------------------------------------------
// DPP helpers. quad_perm: ctrl 0x00-0xFF (sel per lane-in-quad);
// row_shl:k = 0x100|k ; row_shr:k = 0x110|k ; row_mirror = 0x140 ;
// row_half_mirror = 0x141.
// ---------------------------------------------------------------------------
template <int CTRL>
__device__ __forceinline__ float dppm(float x) {
    return __int_as_float(__builtin_amdgcn_mov_dpp(__float_as_int(x), CTRL, 0xF, 0xF, true));
}
// keep-old semantics: lanes with OOB dpp source keep `old` (bound_ctrl=false)
template <int CTRL>
__device__ __forceinline__ float dppk(float old, float x) {
    return __int_as_float(__builtin_amdgcn_update_dpp(
        __float_as_int(old), __float_as_int(x), CTRL, 0xF, 0xF, false));
}

// tanh Pade[5/4]: x(945+105u+u^2)/(945+420u+15u^2), u=x^2. err<=5e-5 on [-2.2,2.2].
__device__ __forceinline__ float tanh_pade(float x) {
    float u = x * x;
    float n = fmaf(u, u + 105.0f, 945.0f);
    float d = fmaf(u, fmaf(u, 15.0f, 420.0f), 945.0f);
    return (x * n) * __builtin_amdgcn_rcpf(d);
}

// async global->LDS, 16 bytes per lane: LDS dest = base + lane*16
__device__ __forceinline__ void gload_lds16(const float* g, float* l) {
    __builtin_amdgcn_global_load_lds(
        (const __attribute__((address_space(1))) void*)g,
        (__attribute__((address_space(3))) void*)l, 16, 0, 0);
}

// ---------------------------------------------------------------------------
// Kernel 1 (r4-proven, unchanged):
// X[row][g] = (inp[row].W_gate[:,q] + b_gate[q] + theta_gate[q]) / 2pi
// ---------------------------------------------------------------------------
__global__ __launch_bounds__(256) void qlstm_xproj(
    const float* __restrict__ inp,
    const float* __restrict__ Wf, const float* __restrict__ bf,
    const float* __restrict__ Wi, const float* __restrict__ bi,
    const float* __restrict__ Wu, const float* __restrict__ bu,
    const float* __restrict__ Wo, const float* __restrict__ bo,
    const float* __restrict__ thf, const float* __restrict__ thi,
    const float* __restrict__ thu, const float* __restrict__ tho,
    float* __restrict__ X)
{
    __shared__ float tile[64 * 129];
    const int tid = threadIdx.x;
    const long long row0 = (long long)blockIdx.x * 64;

    const f4* src = (const f4*)(inp + row0 * IN_DIM);
    #pragma unroll
    for (int i = 0; i < 8; ++i) {
        int f = tid + i * 256;            // 0..2047
        f4 v = __builtin_nontemporal_load(src + f);
        int r = f >> 5, c = (f & 31) << 2;
        float* d = &tile[r * 129 + c];
        d[0] = v.x; d[1] = v.y; d[2] = v.z; d[3] = v.w;
    }
    __syncthreads();

    const int g  = __builtin_amdgcn_readfirstlane(tid >> 6);  // wave id = gate
    const int rl = tid & 63;

    const float* W  = (g == 0) ? Wf : (g == 1) ? Wi : (g == 2) ? Wu : Wo;
    const float* B  = (g == 0) ? bf : (g == 1) ? bi : (g == 2) ? bu : bo;
    const float* TH = (g == 0) ? thf : (g == 1) ? thi : (g == 2) ? thu : tho;

    float acc[8];
    #pragma unroll
    for (int j = 0; j < 8; ++j) acc[j] = B[j] + TH[j];

    #pragma unroll 8
    for (int k = 0; k < IN_DIM; ++k) {
        float v = tile[rl * 129 + k];     // banks (rl+k)%32: 2-way = free
        #pragma unroll
        for (int j = 0; j < 8; ++j)
            acc[j] = fmaf(v, W[k * 8 + j], acc[j]);   // uniform -> s_load
    }

    float4* Xo = (float4*)(X + (row0 + rl) * GDIM + g * 8);
    Xo[0] = make_float4(acc[0] * INV2PI, acc[1] * INV2PI, acc[2] * INV2PI, acc[3] * INV2PI);
    Xo[1] = make_float4(acc[4] * INV2PI, acc[5] * INV2PI, acc[6] * INV2PI, acc[7] * INV2PI);
}

// ---------------------------------------------------------------------------
// Kernel 2: serial recurrence, single-stream layout (r8-proven):
// lane = (stream s = bit5)(batch bb = bit4)(quad qd = bits3:2)(pos p = bits3:0)
//   qubit q = p>>1, gate parity par = bit0; gate = 2s+par.
// Cross-32 gather via v_permlane32_swap_b32 builtin. Semantics: swaps the
// HIGH half of vdst with the LOW half of vsrc, so with both inputs = act:
//   pr[0] = {act.row0, act.row0} ; pr[1] = {act.row1, act.row1}
// -> act[lane^32] = loHalf ? pr[1] : pr[0]   (r10 had the arms inverted,
// which made sw = act (identity) and reproduced r7's exact 0.6558 failure).
// ---------------------------------------------------------------------------
__global__ __launch_bounds__(64, 1) void qlstm_rec(
    const float* __restrict__ X,
    const float* __restrict__ Wf, const float* __restrict__ Wi,
    const float* __restrict__ Wu, const float* __restrict__ Wo,
    float* __restrict__ out)
{
    __shared__ float xb[2 * 2 * 128 * 32];   // [buf][batch][ls][col] = 64 KB

    const int lane = threadIdx.x;
    const int p    = lane & 15;
    const int q    = p >> 1;
    const int par  = lane & 1;
    const int s    = lane >> 5;
    const int bb   = (lane >> 4) & 1;
    const int qd   = (lane >> 2) & 3;
    const int gate = s * 2 + par;
    const int b    = blockIdx.x * 2 + bb;
    const int col  = s * 16 + par * 8 + q;

    const bool isq0   = (q == 0);
    const bool loHalf = (lane < 32);
    const bool sB     = (s == 1);
    const bool parB   = (par == 1);
    const bool strow  = (lane < 32) && (par == 0);   // store lanes

    // per-lane gate weights, permuted to match the broadcast register order
    const float* Wg = (gate == 0) ? Wf : (gate == 1) ? Wi : (gate == 2) ? Wu : Wo;
    float wv[8];
    #pragma unroll
    for (int i = 0; i < 8; ++i)
        wv[i] = Wg[(IN_DIM + (i ^ (qd << 1))) * 8 + q] * INV2PI;

    // activation fold: sigma for f,i,o ; tanh for u
    const bool  isT = (gate == 2);
    const float sc  = isT ? 1.0f : 0.5f;
    const float aa  = isT ? 1.0f : 0.5f;
    const float bbv = isT ? 0.0f : 0.5f;

    // staging: load n of (buf, batch j) : lane i reads
    //   X[(qs + 8n + (i>>3))*SLICE + (2*blk+j)*32 + (i&7)*4 .. +3]
    const float* g0 = X + (lane >> 3) * SLICE + (lane & 7) * 4
                        + blockIdx.x * 2 * GDIM;
    auto stage = [&](int bi, int qs) {
        #pragma unroll
        for (int j = 0; j < 2; ++j) {
            float* dst = &xb[(bi * 2 + j) * 4096];
            const float* srcb = g0 + j * GDIM + qs * SLICE;
            #pragma unroll
            for (int n = 0; n < 16; ++n)
                gload_lds16(srcb + n * 8 * SLICE, dst + n * 256);
        }
    };

    stage(0, 0);
    asm volatile("s_waitcnt vmcnt(0)" ::: "memory");

    const float* xq0 = &xb[bb * 4096 + col];
    float xv0 = xq0[0];
    float xv1 = xq0[32];
    stage(1, 128);

    float hx = 0.0f, cx = 0.0f;
    const float ONE = 1.0f;
    float* outp = out + b * 8 + q;

    for (int qt = 0; qt < 4; ++qt) {
        const int bi = qt & 1;
        const float* xq = &xb[bi * 8192 + bb * 4096 + col];
        if (qt > 0) {
            asm volatile("s_waitcnt vmcnt(0)" ::: "memory");
            xv0 = xq[0];
            xv1 = xq[32];
            if (qt < 3) stage(1 - bi, (qt + 1) * 128);
        }

        auto qstep = [&](int t, int ls, float& XV) {
            float xv = XV;
            XV = xq[((ls + 2) & 127) * 32];       // lookahead refill (wrap-safe)

            // ---- hx broadcast: 8 DPPs, order folded into wv ----
            float Ba = dppm<0x00>(hx);            // h[2*quad]
            float Bb = dppm<0xAA>(hx);            // h[2*quad+1]
            float Bc = dppm<0x141>(Ba);           // h[2q^2]
            float Bd = dppm<0x141>(Bb);           // h[(2q^2)+1]
            float Be = dppm<0x140>(Ba);           // h[2q^6]
            float Bf = dppm<0x140>(Bb);           // h[(2q^6)+1]
            float Bg = dppm<0x141>(Be);           // h[2q^4]
            float Bk = dppm<0x141>(Bf);           // h[(2q^4)+1]

            float mA = fmaf(Ba, wv[0], xv);
            mA = fmaf(Bb, wv[1], mA);
            mA = fmaf(Bc, wv[2], mA);
            mA = fmaf(Bd, wv[3], mA);
            float mB = Be * wv[6];
            mB = fmaf(Bf, wv[7], mB);
            mB = fmaf(Bg, wv[4], mB);
            mB = fmaf(Bk, wv[5], mB);
            float z = mA + mB;

            float cq = __builtin_amdgcn_cosf(z);  // cos(2pi * z')

            // ---- prefix product P_q = c0..cq (stride-2 lanes, keep-old=1) ----
            float P = cq * dppk<0x112>(ONE, cq);
            P = P * dppk<0x114>(ONE, P);
            P = P * dppk<0x118>(ONE, P);

            // ---- strict suffix T_q = c_{q+1}..c7 (parallel to prefix) ----
            float T = dppk<0x102>(ONE, cq);
            T = T * dppk<0x102>(ONE, T);
            T = T * dppk<0x104>(ONE, T);
            T = T * dppk<0x108>(ONE, T);

            float outv = isq0 ? T : P;

            // ---- activation (pade; per-lane sigma/tanh fold) ----
            float act = fmaf(tanh_pade(outv * sc), aa, bbv);

            // ---- gather f,i,u,o for this unit ----
            float n1 = dppm<0xB1>(act);           // other parity, own stream
            // cross-32 exchange: pr[1] low half = act.row1 ; pr[0] high = act.row0
            auto pr = __builtin_amdgcn_permlane32_swap(
                __float_as_int(act), __float_as_int(act), false, false);
            float sw = __int_as_float(loHalf ? pr[1] : pr[0]);  // act[lane^32]
            float sw2 = dppm<0xB1>(sw);           // other stream, other parity

            float X1 = parB ? n1  : act;          // own-stream even gate
            float X2 = parB ? act : n1;           // own-stream odd gate
            float Y1 = parB ? sw2 : sw;           // other-stream even gate
            float Y2 = parB ? sw  : sw2;          // other-stream odd gate

            float fv = sB ? Y1 : X1;
            float iv = sB ? Y2 : X2;
            float uv = sB ? X1 : Y1;
            float ov = sB ? X2 : Y2;

            // ---- state update ----
            float ncx = fmaf(fv, cx, iv * uv);
            float nhx = ov * tanh_pade(ncx);
            cx = ncx;
            hx = nhx;

            if (strow) __builtin_nontemporal_store(nhx, outp + t * (BATCH * 8));
        };

        #pragma unroll 2
        for (int ls = 0; ls < 128; ls += 2) {
            qstep(qt * 128 + ls,     ls,     xv0);
            qstep(qt * 128 + ls + 1, ls + 1, xv1);
        }
    }

    if (strow) {
        __builtin_nontemporal_store(hx, out + T_STEPS * BATCH * 8 + b * 8 + q);
        __builtin_nontemporal_store(cx, out + T_STEPS * BATCH * 8 + (BATCH + b) * 8 + q);
    }
}

// ---------------------------------------------------------------------------
extern "C" void kernel_launch(void* const* d_in, const int* in_sizes, int n_in,
                              void* d_out, int out_size, void* d_ws, size_t ws_size,
                              hipStream_t stream) {
    const float* inp = (const float*)d_in[0];
    const float* Wf  = (const float*)d_in[1];
    const float* bf  = (const float*)d_in[2];
    const float* Wi  = (const float*)d_in[3];
    const float* bi  = (const float*)d_in[4];
    const float* Wu  = (const float*)d_in[5];
    const float* bu  = (const float*)d_in[6];
    const float* Wo  = (const float*)d_in[7];
    const float* bo  = (const float*)d_in[8];
    const float* thf = (const float*)d_in[9];
    const float* thi = (const float*)d_in[10];
    const float* thu = (const float*)d_in[11];
    const float* tho = (const float*)d_in[12];

    float* X   = (float*)d_ws;              // (T*B, 32) fp32 = 33.5 MB
    float* out = (float*)d_out;

    qlstm_xproj<<<(T_STEPS * BATCH) / 64, 256, 0, stream>>>(
        inp, Wf, bf, Wi, bi, Wu, bu, Wo, bo, thf, thi, thu, tho, X);

    qlstm_rec<<<BATCH / 2, 64, 0, stream>>>(X, Wf, Wi, Wu, Wo, out);
}

// Round 13
// 130.650 us; speedup vs baseline: 1.3946x; 1.1434x over previous
//
#include <hip/hip_runtime.h>
#include <stdint.h>

#define T_STEPS 512
#define BATCH   512
#define IN_DIM  128
#define GDIM    32   // 4 gates x 8 qubits
#define SLICE   (BATCH * GDIM)   // 16384 floats per time step
#define INV2PI  0.15915494309189535f

typedef float f4 __attribute__((ext_vector_type(4)));

// ---------------------------------------------------------------------------
// DPP helpers. Conventions PROVEN by passing kernels (r8/r11):
//   row_shl:k (0x100|k): dst i <- src i+k   (OOB top lanes)
//   row_shr:k (0x110|k): dst i <- src i-k   (OOB bottom lanes)
//   row_mirror 0x140: dst i <- src 15-i ; row_half_mirror 0x141: i^7 in 8.
//   quad_perm 0xB1: pair swap (dst i <- src i^1).
// ---------------------------------------------------------------------------
template <int CTRL>
__device__ __forceinline__ float dppm(float x) {
    return __int_as_float(__builtin_amdgcn_mov_dpp(__float_as_int(x), CTRL, 0xF, 0xF, true));
}
// keep-old semantics: lanes with OOB dpp source keep `old` (bound_ctrl=false)
template <int CTRL>
__device__ __forceinline__ float dppk(float old, float x) {
    return __int_as_float(__builtin_amdgcn_update_dpp(
        __float_as_int(old), __float_as_int(x), CTRL, 0xF, 0xF, false));
}

// tanh Pade[5/4]: x(945+105u+u^2)/(945+420u+15u^2), u=x^2. err<=5e-5 on [-2.2,2.2].
__device__ __forceinline__ float tanh_pade(float x) {
    float u = x * x;
    float n = fmaf(u, u + 105.0f, 945.0f);
    float d = fmaf(u, fmaf(u, 15.0f, 420.0f), 945.0f);
    return (x * n) * __builtin_amdgcn_rcpf(d);
}

// tanh odd poly deg-7 for |x|<=1 (pure FMA, no rcp): err <= ~2e-4.
__device__ __forceinline__ float tanh_poly1(float x) {
    float u = x * x;
    float h = fmaf(u, fmaf(u, fmaf(u, -0.0277f, 0.1204402f), -0.3310474f), 0.9999014f);
    return x * h;
}

// async global->LDS, 16 bytes per lane: LDS dest = base + lane*16
__device__ __forceinline__ void gload_lds16(const float* g, float* l) {
    __builtin_amdgcn_global_load_lds(
        (const __attribute__((address_space(1))) void*)g,
        (__attribute__((address_space(3))) void*)l, 16, 0, 0);
}

// ---------------------------------------------------------------------------
// Kernel 1 (r4-proven, unchanged):
// X[row][g] = (inp[row].W_gate[:,q] + b_gate[q] + theta_gate[q]) / 2pi
// ---------------------------------------------------------------------------
__global__ __launch_bounds__(256) void qlstm_xproj(
    const float* __restrict__ inp,
    const float* __restrict__ Wf, const float* __restrict__ bf,
    const float* __restrict__ Wi, const float* __restrict__ bi,
    const float* __restrict__ Wu, const float* __restrict__ bu,
    const float* __restrict__ Wo, const float* __restrict__ bo,
    const float* __restrict__ thf, const float* __restrict__ thi,
    const float* __restrict__ thu, const float* __restrict__ tho,
    float* __restrict__ X)
{
    __shared__ float tile[64 * 129];
    const int tid = threadIdx.x;
    const long long row0 = (long long)blockIdx.x * 64;

    const f4* src = (const f4*)(inp + row0 * IN_DIM);
    #pragma unroll
    for (int i = 0; i < 8; ++i) {
        int f = tid + i * 256;            // 0..2047
        f4 v = __builtin_nontemporal_load(src + f);
        int r = f >> 5, c = (f & 31) << 2;
        float* d = &tile[r * 129 + c];
        d[0] = v.x; d[1] = v.y; d[2] = v.z; d[3] = v.w;
    }
    __syncthreads();

    const int g  = __builtin_amdgcn_readfirstlane(tid >> 6);  // wave id = gate
    const int rl = tid & 63;

    const float* W  = (g == 0) ? Wf : (g == 1) ? Wi : (g == 2) ? Wu : Wo;
    const float* B  = (g == 0) ? bf : (g == 1) ? bi : (g == 2) ? bu : bo;
    const float* TH = (g == 0) ? thf : (g == 1) ? thi : (g == 2) ? thu : tho;

    float acc[8];
    #pragma unroll
    for (int j = 0; j < 8; ++j) acc[j] = B[j] + TH[j];

    #pragma unroll 8
    for (int k = 0; k < IN_DIM; ++k) {
        float v = tile[rl * 129 + k];     // banks (rl+k)%32: 2-way = free
        #pragma unroll
        for (int j = 0; j < 8; ++j)
            acc[j] = fmaf(v, W[k * 8 + j], acc[j]);   // uniform -> s_load
    }

    float4* Xo = (float4*)(X + (row0 + rl) * GDIM + g * 8);
    Xo[0] = make_float4(acc[0] * INV2PI, acc[1] * INV2PI, acc[2] * INV2PI, acc[3] * INV2PI);
    Xo[1] = make_float4(acc[4] * INV2PI, acc[5] * INV2PI, acc[6] * INV2PI, acc[7] * INV2PI);
}

// ---------------------------------------------------------------------------
// Kernel 2: serial recurrence, single-stream layout (r11-proven) with:
//  (a) suffix scan removed: q=0 output = fullprod * rcp(c0). Full product
//      (at p=14/15 after the prefix scan) is broadcast to p=0/1 via
//      row_mirror(0x140) + pair-swap(0xB1) — BOTH proven primitives,
//      parity-preserving. (r12's row_ror:14 had the direction inverted:
//      ror:n = dst i <- src (i-n)&15, so it read the q=1 prefix.)
//  (b) activation tanh = pure-FMA poly (no rcp); update keeps Pade.
//  (c) all-lane stores (values replicated across (s,par) per (bb,q)).
// ---------------------------------------------------------------------------
__global__ __launch_bounds__(64, 1) void qlstm_rec(
    const float* __restrict__ X,
    const float* __restrict__ Wf, const float* __restrict__ Wi,
    const float* __restrict__ Wu, const float* __restrict__ Wo,
    float* __restrict__ out)
{
    __shared__ float xb[2 * 2 * 128 * 32];   // [buf][batch][ls][col] = 64 KB

    const int lane = threadIdx.x;
    const int p    = lane & 15;
    const int q    = p >> 1;
    const int par  = lane & 1;
    const int s    = lane >> 5;
    const int bb   = (lane >> 4) & 1;
    const int qd   = (lane >> 2) & 3;
    const int gate = s * 2 + par;
    const int b    = blockIdx.x * 2 + bb;
    const int col  = s * 16 + par * 8 + q;

    const bool isq0   = (q == 0);
    const bool loHalf = (lane < 32);
    const bool sB     = (s == 1);
    const bool parB   = (par == 1);

    // per-lane gate weights, permuted to match the broadcast register order
    const float* Wg = (gate == 0) ? Wf : (gate == 1) ? Wi : (gate == 2) ? Wu : Wo;
    float wv[8];
    #pragma unroll
    for (int i = 0; i < 8; ++i)
        wv[i] = Wg[(IN_DIM + (i ^ (qd << 1))) * 8 + q] * INV2PI;

    // activation fold: sigma for f,i,o ; tanh for u
    const bool  isT = (gate == 2);
    const float sc  = isT ? 1.0f : 0.5f;
    const float aa  = isT ? 1.0f : 0.5f;
    const float bbv = isT ? 0.0f : 0.5f;

    // staging: load n of (buf, batch j) : lane i reads
    //   X[(qs + 8n + (i>>3))*SLICE + (2*blk+j)*32 + (i&7)*4 .. +3]
    const float* g0 = X + (lane >> 3) * SLICE + (lane & 7) * 4
                        + blockIdx.x * 2 * GDIM;
    auto stage = [&](int bi, int qs) {
        #pragma unroll
        for (int j = 0; j < 2; ++j) {
            float* dst = &xb[(bi * 2 + j) * 4096];
            const float* srcb = g0 + j * GDIM + qs * SLICE;
            #pragma unroll
            for (int n = 0; n < 16; ++n)
                gload_lds16(srcb + n * 8 * SLICE, dst + n * 256);
        }
    };

    stage(0, 0);
    asm volatile("s_waitcnt vmcnt(0)" ::: "memory");

    const float* xq0 = &xb[bb * 4096 + col];
    float xv0 = xq0[0];
    float xv1 = xq0[32];
    stage(1, 128);

    float hx = 0.0f, cx = 0.0f;
    const float ONE = 1.0f;
    float* outp = out + b * 8 + q;

    for (int qt = 0; qt < 4; ++qt) {
        const int bi = qt & 1;
        const float* xq = &xb[bi * 8192 + bb * 4096 + col];
        if (qt > 0) {
            asm volatile("s_waitcnt vmcnt(0)" ::: "memory");
            xv0 = xq[0];
            xv1 = xq[32];
            if (qt < 3) stage(1 - bi, (qt + 1) * 128);
        }

        auto qstep = [&](int t, int ls, float& XV) {
            float xv = XV;
            XV = xq[((ls + 2) & 127) * 32];       // lookahead refill (wrap-safe)

            // ---- hx broadcast: 8 DPPs, order folded into wv ----
            float Ba = dppm<0x00>(hx);            // h[2*quad]
            float Bb = dppm<0xAA>(hx);            // h[2*quad+1]
            float Bc = dppm<0x141>(Ba);           // h[2q^2]
            float Bd = dppm<0x141>(Bb);           // h[(2q^2)+1]
            float Be = dppm<0x140>(Ba);           // h[2q^6]
            float Bf = dppm<0x140>(Bb);           // h[(2q^6)+1]
            float Bg = dppm<0x141>(Be);           // h[2q^4]
            float Bk = dppm<0x141>(Bf);           // h[(2q^4)+1]

            float mA = fmaf(Ba, wv[0], xv);
            mA = fmaf(Bb, wv[1], mA);
            mA = fmaf(Bc, wv[2], mA);
            mA = fmaf(Bd, wv[3], mA);
            float mB = Be * wv[6];
            mB = fmaf(Bf, wv[7], mB);
            mB = fmaf(Bg, wv[4], mB);
            mB = fmaf(Bk, wv[5], mB);
            float z = mA + mB;

            float cq = __builtin_amdgcn_cosf(z);  // cos(2pi * z')

            // off-path: rcp of own cosine (q=0 lanes use it; clamped vs 0)
            float cc  = fabsf(cq) < 1e-30f ? 1e-30f : cq;
            float rcpc = __builtin_amdgcn_rcpf(cc);

            // ---- prefix product P_q = c0..cq (stride-2 lanes, keep-old=1) ----
            float P = cq * dppk<0x112>(ONE, cq);
            P = P * dppk<0x114>(ONE, P);
            P = P * dppk<0x118>(ONE, P);

            // ---- q=0 output: fullprod (p=14/15) -> p=0/1 via mirror+swap ----
            float Pm    = dppm<0x140>(P);         // Pm[p] = P[15-p]
            float Pfull = dppm<0xB1>(Pm);         // Pfull[0]=P[14], [1]=P[15]
            float out0  = Pfull * rcpc;
            float outv  = isq0 ? out0 : P;

            // ---- activation: pure-FMA tanh poly (|outv*sc| <= 1) ----
            float act = fmaf(tanh_poly1(outv * sc), aa, bbv);

            // ---- gather f,i,u,o for this unit ----
            float n1 = dppm<0xB1>(act);           // other parity, own stream
            // cross-32 exchange: pr[1] low half = act.row1 ; pr[0] high = act.row0
            auto pr = __builtin_amdgcn_permlane32_swap(
                __float_as_int(act), __float_as_int(act), false, false);
            float sw = __int_as_float(loHalf ? pr[1] : pr[0]);  // act[lane^32]
            float sw2 = dppm<0xB1>(sw);           // other stream, other parity

            float X1 = parB ? n1  : act;          // own-stream even gate
            float X2 = parB ? act : n1;           // own-stream odd gate
            float Y1 = parB ? sw2 : sw;           // other-stream even gate
            float Y2 = parB ? sw  : sw2;          // other-stream odd gate

            float fv = sB ? Y1 : X1;
            float iv = sB ? Y2 : X2;
            float uv = sB ? X1 : Y1;
            float ov = sB ? X2 : Y2;

            // ---- state update ----
            float ncx = fmaf(fv, cx, iv * uv);
            float nhx = ov * tanh_pade(ncx);
            cx = ncx;
            hx = nhx;

            // all lanes store: 4 lanes per (bb,q) write the same value
            __builtin_nontemporal_store(nhx, outp + t * (BATCH * 8));
        };

        #pragma unroll 2
        for (int ls = 0; ls < 128; ls += 2) {
            qstep(qt * 128 + ls,     ls,     xv0);
            qstep(qt * 128 + ls + 1, ls + 1, xv1);
        }
    }

    __builtin_nontemporal_store(hx, out + T_STEPS * BATCH * 8 + b * 8 + q);
    __builtin_nontemporal_store(cx, out + T_STEPS * BATCH * 8 + (BATCH + b) * 8 + q);
}

// ---------------------------------------------------------------------------
extern "C" void kernel_launch(void* const* d_in, const int* in_sizes, int n_in,
                              void* d_out, int out_size, void* d_ws, size_t ws_size,
                              hipStream_t stream) {
    const float* inp = (const float*)d_in[0];
    const float* Wf  = (const float*)d_in[1];
    const float* bf  = (const float*)d_in[2];
    const float* Wi  = (const float*)d_in[3];
    const float* bi  = (const float*)d_in[4];
    const float* Wu  = (const float*)d_in[5];
    const float* bu  = (const float*)d_in[6];
    const float* Wo  = (const float*)d_in[7];
    const float* bo  = (const float*)d_in[8];
    const float* thf = (const float*)d_in[9];
    const float* thi = (const float*)d_in[10];
    const float* thu = (const float*)d_in[11];
    const float* tho = (const float*)d_in[12];

    float* X   = (float*)d_ws;              // (T*B, 32) fp32 = 33.5 MB
    float* out = (float*)d_out;

    qlstm_xproj<<<(T_STEPS * BATCH) / 64, 256, 0, stream>>>(
        inp, Wf, bf, Wi, bi, Wu, bu, Wo, bo, thf, thi, thu, tho, X);

    qlstm_rec<<<BATCH / 2, 64, 0, stream>>>(X, Wf, Wi, Wu, Wo, out);
}